// Round 1
// baseline (82.683 us; speedup 1.0000x reference)
//
#include <hip/hip_runtime.h>
#include <math.h>

// PartialChamferLoss: B=2, N=8192, M=32768, S=4096.
// d2 = |x|^2 + |y|^2 - 2 x.y ; min over M per query ; mean(sqrt).
// R9: profile shows timed region = ~40us harness ws-poison fill (268MB,
// outside .cpp control) + ~39us chamfer_main (just below the fills in
// top-5) + ~3us tail. Main's VALU floor is ~14us -> attack the non-VALU
// pipes:
//  (a) staging: 48x 12B-stride scalar loads (12-line txns each) -> 12x
//      float4 loads; lane now owns 4 CONSECUTIVE targets (12 contiguous
//      floats = 3 float4), repacked in-register. Chunk-min is coverage-
//      only, so the lane<->target remap is free.
//  (b) query ring: SoA 3x ds_read_b32/step -> AoS float4, 1x ds_read_b128.
//      |x|^2 rides in .w (read once). LDS ops/step 4 -> 2.
//  (c) finish: uint4 loads.
// Kept from R8: named-register targets (R=16, no spill), #pragma unroll 1,
// __launch_bounds__(256,4), ds_bpermute traveling min, per-block query
// gather, 32KB memset-0xFF wsmin init, separate finish dispatch.
typedef float vf2 __attribute__((ext_vector_type(2)));
typedef float vf4 __attribute__((ext_vector_type(4)));

constexpr int B = 2;
constexpr int N = 8192;
constexpr int M = 32768;
constexpr int S = 4096;
constexpr int QTOT = B * S;          // 8192 queries
constexpr int R = 16;                // targets per lane (no spill at 16)
constexpr int WT = 64 * R;           // 1024 targets per wave
constexpr int TCH = M / WT;          // 32 target chunks per batch
constexpr int QG = S / 64;           // 64 query groups per batch
constexpr int WAVES = B * TCH * QG;  // 4096 waves
constexpr int BLOCKS = WAVES / 4;    // 1024 blocks x 256 threads

#define DECLP(j) vf2 T0_##j, T1_##j, T2_##j, TY_##j;

// Load 4 consecutive targets (12 contiguous floats = 3 float4) for this
// lane and repack into two vf2 pairs pA=(t0,t1), pB=(t2,t3).
// Row r covers targets [256r, 256r+256); lane l owns 256r+4l .. +3.
#define LOADQUAD(r, pA, pB)                                               \
  {                                                                       \
    vf4 u0 = gt[192 * (r) + 3 * lane];                                    \
    vf4 u1 = gt[192 * (r) + 3 * lane + 1];                                \
    vf4 u2 = gt[192 * (r) + 3 * lane + 2];                                \
    T0_##pA = vf2{u0.x, u0.w};                                            \
    T1_##pA = vf2{u0.y, u1.x};                                            \
    T2_##pA = vf2{u0.z, u1.y};                                            \
    TY_##pA = vf2{fmaf(u0.x, u0.x, fmaf(u0.y, u0.y, u0.z * u0.z)),        \
                  fmaf(u0.w, u0.w, fmaf(u1.x, u1.x, u1.y * u1.y))};       \
    T0_##pB = vf2{u1.z, u2.y};                                            \
    T1_##pB = vf2{u1.w, u2.z};                                            \
    T2_##pB = vf2{u2.x, u2.w};                                            \
    TY_##pB = vf2{fmaf(u1.z, u1.z, fmaf(u1.w, u1.w, u2.x * u2.x)),        \
                  fmaf(u2.y, u2.y, fmaf(u2.z, u2.z, u2.w * u2.w))};       \
  }

#define PAIRC(j, acc)                                                    \
  {                                                                      \
    vf2 s = __builtin_elementwise_fma(Q0, T0_##j, TY_##j);               \
    s = __builtin_elementwise_fma(Q1, T1_##j, s);                        \
    s = __builtin_elementwise_fma(Q2, T2_##j, s);                        \
    acc = fminf(fminf(s.x, s.y), acc); /* v_min3_f32 */                  \
  }

__global__ __launch_bounds__(256, 4) void chamfer_main(
    const float* __restrict__ pred, const float* __restrict__ target,
    const int* __restrict__ idx, unsigned* __restrict__ wsmin) {
  __shared__ vf4 qv[64];  // {-2x, -2y, -2z, |x|^2} per query
  const int lane = threadIdx.x & 63;
  const int w = blockIdx.x * 4 + (threadIdx.x >> 6);  // 0..4095
  const int b = w >> 11;
  const int rem = w & 2047;
  const int tch = rem & (TCH - 1);  // varies across block's 4 waves
  const int qg = rem >> 5;          // uniform across block (4 | TCH)

  // Gather this block's query group directly from pred[idx] (L2-hot).
  if (threadIdx.x < 64) {
    int s = qg * 64 + threadIdx.x;
    int i = idx[s];
    const float* p = pred + ((size_t)b * N + (size_t)i) * 3;
    float x = p[0], y = p[1], z = p[2];
    qv[threadIdx.x] =
        vf4{-2.0f * x, -2.0f * y, -2.0f * z, fmaf(x, x, fmaf(y, y, z * z))};
  }

  // Stage this lane's 16 targets (4 rows x 4 consecutive targets) into
  // NAMED registers via 12 coalesced-ish float4 loads.
  const float* tb = target + ((size_t)b * M + (size_t)tch * WT) * 3;
  const vf4* gt = (const vf4*)tb;
  DECLP(0) DECLP(1) DECLP(2) DECLP(3) DECLP(4) DECLP(5) DECLP(6) DECLP(7)
  LOADQUAD(0, 0, 1) LOADQUAD(1, 2, 3) LOADQUAD(2, 4, 5) LOADQUAD(3, 6, 7)
  __syncthreads();

  const vf4 qh = qv[lane];                // own query record (.w = |x|^2)
  const int rot = ((lane + 1) & 63) * 4;  // bpermute byte-addr: pull lane+1
  float mm = INFINITY;                    // traveling min of (|y|^2 - 2x.y)
  int qoff = lane;
  vf4 qc = qh;

#pragma unroll 1  // keep the 32 vf2 target regs' live ranges tight
  for (int step = 0; step < 64; ++step) {
    // Prefetch next query (single ds_read_b128 hides under 8-pair compute).
    const int qn = (qoff + 1) & 63;
    vf4 nq = qv[qn];
    const vf2 Q0 = vf2{qc.x, qc.x};
    const vf2 Q1 = vf2{qc.y, qc.y};
    const vf2 Q2 = vf2{qc.z, qc.z};
    float m0 = INFINITY, m1 = INFINITY;
    PAIRC(0, m0) PAIRC(1, m1) PAIRC(2, m0) PAIRC(3, m1)
    PAIRC(4, m0) PAIRC(5, m1) PAIRC(6, m0) PAIRC(7, m1)
    // Incoming traveling min (prev step's bpermute) consumed only here.
    mm = fminf(mm, fminf(m0, m1));
    mm = __int_as_float(__builtin_amdgcn_ds_bpermute(rot, __float_as_int(mm)));
    qc = nq;
    qoff = qn;
  }
  // After 64 rotations the own query's complete chunk-min is back home.
  const int q = b * S + qg * 64 + lane;
  atomicMin(&wsmin[q], __float_as_uint(fmaxf(qh.w + mm, 0.0f)));
}

__global__ __launch_bounds__(1024) void chamfer_finish(
    const unsigned* __restrict__ wsmin, float* __restrict__ out) {
  __shared__ float red[16];
  const uint4* wm = (const uint4*)wsmin;
  float sum = 0.0f;
#pragma unroll
  for (int i = 0; i < QTOT / 4096; ++i) {  // 2x uint4 per thread
    uint4 v = wm[threadIdx.x + i * 1024];
    sum += sqrtf(__uint_as_float(v.x)) + sqrtf(__uint_as_float(v.y)) +
           sqrtf(__uint_as_float(v.z)) + sqrtf(__uint_as_float(v.w));
  }
#pragma unroll
  for (int off = 32; off > 0; off >>= 1)
    sum += __shfl_down(sum, off, 64);
  int wv = threadIdx.x >> 6;
  if ((threadIdx.x & 63) == 0) red[wv] = sum;
  __syncthreads();
  if (threadIdx.x == 0) {
    float t = 0.0f;
#pragma unroll
    for (int i = 0; i < 16; ++i) t += red[i];
    out[0] = t / (float)QTOT;
  }
}

extern "C" void kernel_launch(void* const* d_in, const int* in_sizes, int n_in,
                              void* d_out, int out_size, void* d_ws, size_t ws_size,
                              hipStream_t stream) {
  const float* pred = (const float*)d_in[0];
  const float* target = (const float*)d_in[1];
  const int* idx = (const int*)d_in[2];
  unsigned* wsmin = (unsigned*)d_ws;

  hipMemsetAsync(wsmin, 0xFF, QTOT * sizeof(unsigned), stream);
  chamfer_main<<<BLOCKS, 256, 0, stream>>>(pred, target, idx, wsmin);
  chamfer_finish<<<1, 1024, 0, stream>>>(wsmin, (float*)d_out);
}